// Round 8
// baseline (137.150 us; speedup 1.0000x reference)
//
#include <hip/hip_runtime.h>
#include <math.h>

#define NB 16
#define CF 64
#define LL 16384
#define GG 8
#define NH 2
#define CHN 64
#define NCH 256
#define NGRP 16

static constexpr size_t OFF_GT = 0;
static constexpr size_t OFF_U2 = OFF_GT + (size_t)NB*LL*GG;
static constexpr size_t OFF_AC = OFF_U2 + (size_t)NB*NCH*256;
static constexpr size_t OFF_PH = OFF_AC + (size_t)NB*NCH*NH;
static constexpr size_t OFF_CP = OFF_PH + (size_t)NB*NCH*256;
static constexpr size_t OFF_UG = OFF_CP + (size_t)NB*NCH*NH;
static constexpr size_t OFF_AG = OFF_UG + (size_t)NB*NGRP*256;
static constexpr size_t OFF_GH = OFF_AG + (size_t)NB*NGRP*NH;
static constexpr size_t OFF_G2 = OFF_GH + (size_t)NB*NGRP*256;
static constexpr size_t WS_FLOATS = OFF_G2 + (size_t)NB*LL*GG;

typedef float f32x4 __attribute__((ext_vector_type(4)));
typedef short bf16x8 __attribute__((ext_vector_type(8)));

__device__ __forceinline__ float siluf(float v){ return v / (1.f + __expf(-v)); }
__device__ __forceinline__ float softplusf(float v){ return v > 20.f ? v : log1pf(__expf(v)); }

__device__ __forceinline__ unsigned short f2bf(float f){
    unsigned int u = __float_as_uint(f);
    u += 0x7fffu + ((u >> 16) & 1u);
    return (unsigned short)(u >> 16);
}
__device__ __forceinline__ float bf2f(unsigned short s){
    return __uint_as_float(((unsigned int)s) << 16);
}
__device__ __forceinline__ unsigned int pack2bf(float lo, float hi){
    return (unsigned int)f2bf(lo) | ((unsigned int)f2bf(hi) << 16);
}

__device__ __forceinline__ void load8(float* d, const float* p){
    float4 a = ((const float4*)p)[0];
    float4 b = ((const float4*)p)[1];
    d[0]=a.x; d[1]=a.y; d[2]=a.z; d[3]=a.w;
    d[4]=b.x; d[5]=b.y; d[6]=b.z; d[7]=b.w;
}

// K1a: tokenize x -> gt.  1024 blocks x 64 threads, 4 l per thread.
__global__ __launch_bounds__(64) void k1a_tok(
    const float* __restrict__ x, const float* __restrict__ tok_w,
    const float* __restrict__ tok_b, float* __restrict__ gtw)
{
    __shared__ float s_tok[GG*CF];
    int tid = threadIdx.x;
    int b  = blockIdx.x >> 6;
    int ck = blockIdx.x & 63;
    int l0 = (ck << 8) + (tid << 2);
    for (int i = tid; i < GG*CF; i += 64) s_tok[i] = tok_w[i];
    __syncthreads();
    float acc[4][GG];
    #pragma unroll
    for (int r = 0; r < 4; ++r)
        #pragma unroll
        for (int g = 0; g < GG; ++g) acc[r][g] = tok_b[g];
    const float* xb = x + (size_t)b*CF*LL + l0;
    #pragma unroll 8
    for (int c = 0; c < CF; ++c) {
        float4 xv = *(const float4*)(xb + (size_t)c*LL);
        float xa[4] = {xv.x, xv.y, xv.z, xv.w};
        #pragma unroll
        for (int g = 0; g < GG; ++g) {
            float w = s_tok[g*CF + c];
            #pragma unroll
            for (int r = 0; r < 4; ++r) acc[r][g] = fmaf(xa[r], w, acc[r][g]);
        }
    }
    float* gp = gtw + ((size_t)b*LL + l0)*GG;
    #pragma unroll
    for (int r = 0; r < 4; ++r) {
        ((float4*)gp)[r*2+0] = make_float4(acc[r][0],acc[r][1],acc[r][2],acc[r][3]);
        ((float4*)gp)[r*2+1] = make_float4(acc[r][4],acc[r][5],acc[r][6],acc[r][7]);
    }
}

// K2a: pass A — chunk end-state only. Stage x,B,dt; cumsum; 2 MFMAs -> U2, Ac.
__global__ __launch_bounds__(256) void k2a_state(
    const float* __restrict__ gtw,
    const float* __restrict__ ipw, const float* __restrict__ ipb,
    const float* __restrict__ cw, const float* __restrict__ cb,
    const float* __restrict__ A_log, const float* __restrict__ dt_bias,
    float* __restrict__ U2w, float* __restrict__ Acw)
{
    __shared__ __align__(16) unsigned short XTbf[16*72];  // x^T[p][s]
    __shared__ __align__(16) unsigned short BTbf[16*72];  // B^T[n][s]
    __shared__ __align__(16) unsigned short WXbf[16*72];  // (w*x)^T[p][s]
    __shared__ float s_dt[64][2], s_nda[64][2];
    __shared__ float s_ipw[256], s_ipb2[32], s_cw2[96], s_cb2[32], s_wdt[16];

    int tid = threadIdx.x;
    int b = blockIdx.x >> 8, c = blockIdx.x & 255;
    s_ipw[tid] = ipw[128 + tid];
    if (tid < 32) { s_ipb2[tid] = ipb[16 + tid]; s_cb2[tid] = cb[tid]; }
    else if (tid >= 64 && tid < 160) s_cw2[tid - 64] = cw[tid - 64];
    else if (tid >= 224 && tid < 240) s_wdt[tid - 224] = ipw[512 + (tid - 224)];
    __syncthreads();                                          // B0

    float a0e = __expf(A_log[0]), a1e = __expf(A_log[1]);
    float dtb0 = dt_bias[0], dtb1 = dt_bias[1];
    float bdt0 = ipb[64], bdt1 = ipb[65];

    {   // staging: lane (r, sub) does 8 channels of {x,B}
        int r = tid >> 2, sub = tid & 3;
        int l = c*CHN + r;
        size_t gb = ((size_t)b*LL + l)*GG;
        float g0[8], g1[8], g2v[8];
        #pragma unroll
        for (int g = 0; g < 8; ++g) { g1[g] = 0.f; g2v[g] = 0.f; }
        load8(g0, gtw + gb);
        if (l >= 1) load8(g1, gtw + gb - GG);
        if (l >= 2) load8(g2v, gtw + gb - 2*GG);
        #pragma unroll
        for (int k = 0; k < 8; ++k) {
            int ch = sub*8 + k;          // 0..31: x 0..15, B 16..31
            float bia = s_ipb2[ch];
            float tA = bia, tB = bia, tC = bia;
            #pragma unroll
            for (int g = 0; g < 8; ++g) {
                float wv = s_ipw[ch*8+g];
                tA = fmaf(g0[g],  wv, tA);
                tB = fmaf(g1[g],  wv, tB);
                tC = fmaf(g2v[g], wv, tC);
            }
            if (l < 1) tB = 0.f;
            if (l < 2) tC = 0.f;
            float a = s_cb2[ch];
            a = fmaf(tC, s_cw2[ch*3+0], a);
            a = fmaf(tB, s_cw2[ch*3+1], a);
            a = fmaf(tA, s_cw2[ch*3+2], a);
            float v = siluf(a);
            if (ch < 16) XTbf[ch*72 + r] = f2bf(v);
            else         BTbf[(ch-16)*72 + r] = f2bf(v);
        }
        if (sub == 0) {
            float d0 = bdt0, d1 = bdt1;
            #pragma unroll
            for (int g = 0; g < 8; ++g) {
                d0 = fmaf(g0[g], s_wdt[g],   d0);
                d1 = fmaf(g0[g], s_wdt[8+g], d1);
            }
            float dt0 = softplusf(d0 + dtb0), dt1 = softplusf(d1 + dtb1);
            s_dt[r][0] = dt0; s_dt[r][1] = dt1;
            s_nda[r][0] = -dt0*a0e; s_nda[r][1] = -dt1*a1e;
        }
    }
    __syncthreads();                                          // B1

    if (tid < 64) {   // wave 0 finishes alone: cumsum, WX, MFMA, stores
        int rr = tid;
        float v0 = s_nda[rr][0], v1 = s_nda[rr][1];
        #pragma unroll
        for (int off = 1; off < 64; off <<= 1) {
            float t0 = __shfl_up(v0, off);
            float t1 = __shfl_up(v1, off);
            if (rr >= off) { v0 += t0; v1 += t1; }
        }
        float f0 = __shfl(v0, 63), f1 = __shfl(v1, 63);
        float w0 = __expf(f0 - v0) * s_dt[rr][0];
        float w1 = __expf(f1 - v1) * s_dt[rr][1];
        if (rr == 63)
            *(float2*)(Acw + ((size_t)b*NCH + c)*2) = make_float2(__expf(f0), __expf(f1));
        #pragma unroll
        for (int pp = 0; pp < 16; ++pp) {
            float wh = (pp < 8) ? w0 : w1;
            WXbf[pp*72 + rr] = f2bf(wh * bf2f(XTbf[pp*72 + rr]));
        }
        int ar = tid & 15, kb = tid >> 4;
        f32x4 acc = {0.f, 0.f, 0.f, 0.f};
        #pragma unroll
        for (int kk = 0; kk < 2; ++kk) {
            bf16x8 aw = *(const bf16x8*)&WXbf[ar*72 + kk*32 + kb*8];
            bf16x8 bb = *(const bf16x8*)&BTbf[ar*72 + kk*32 + kb*8];
            acc = __builtin_amdgcn_mfma_f32_16x16x32_bf16(aw, bb, acc, 0, 0, 0);
        }
        #pragma unroll
        for (int rg = 0; rg < 4; ++rg)
            U2w[(((size_t)b*NCH + c) << 8) + (kb*4+rg)*16 + ar] = acc[rg];
    }
}

// K4c1: scan 16 chunks within each group (states preloaded).
__global__ void k4c1(const float* __restrict__ U2w, const float* __restrict__ Acw,
                     float* __restrict__ phw, float* __restrict__ cpw,
                     float* __restrict__ Ugw, float* __restrict__ Agw)
{
    int b = blockIdx.x >> 4, grp = blockIdx.x & 15;
    int e = threadIdx.x, he = e >> 7;
    size_t base = (size_t)b*NCH + grp*16;
    float u[16], A[16];
    #pragma unroll
    for (int j = 0; j < 16; ++j) u[j] = U2w[((base + j) << 8) + e];
    #pragma unroll
    for (int j = 0; j < 16; ++j) A[j] = Acw[(base + j)*2 + he];
    float h = 0.f, cp = 1.f;
    #pragma unroll
    for (int j = 0; j < 16; ++j) {
        phw[((base + j) << 8) + e] = h;
        if ((e & 127) == 0) cpw[(base + j)*2 + he] = cp;
        h = fmaf(A[j], h, u[j]);
        cp *= A[j];
    }
    Ugw[(((size_t)b*NGRP + grp) << 8) + e] = h;
    if ((e & 127) == 0) Agw[((size_t)b*NGRP + grp)*2 + he] = cp;
}

// K4c2: scan 16 group summaries.
__global__ void k4c2(const float* __restrict__ Ugw, const float* __restrict__ Agw,
                     float* __restrict__ ghw)
{
    int b = blockIdx.x, e = threadIdx.x, he = e >> 7;
    float u[NGRP], ag[NGRP];
    #pragma unroll
    for (int g = 0; g < NGRP; ++g) {
        u[g]  = Ugw[(((size_t)b*NGRP + g) << 8) + e];
        ag[g] = Agw[((size_t)b*NGRP + g)*2 + he];
    }
    float h = 0.f;
    #pragma unroll
    for (int g = 0; g < NGRP; ++g) {
        ghw[(((size_t)b*NGRP + g) << 8) + e] = h;
        h = fmaf(ag[g], h, u[g]);
    }
}

// K2b: pass B — full SSD + hin correction + epilogue -> g2.
__global__ __launch_bounds__(256) void k2b_fused(
    const float* __restrict__ gtw,
    const float* __restrict__ ipw, const float* __restrict__ ipb,
    const float* __restrict__ cw, const float* __restrict__ cb,
    const float* __restrict__ A_log, const float* __restrict__ dt_bias,
    const float* __restrict__ Dv, const float* __restrict__ norm_w,
    const float* __restrict__ out_w, const float* __restrict__ out_b,
    const float* __restrict__ phw, const float* __restrict__ cpw,
    const float* __restrict__ ghw,
    float* __restrict__ g2w)
{
    __shared__ __align__(16) unsigned short Cbf[64*40];   // C[t][n], cols 16..31 zero (yb overlays later)
    __shared__ __align__(16) unsigned short Bbf[64*40];   // B[s][n], cols 16..31 zero
    __shared__ __align__(16) unsigned short XTbf[16*72];  // x^T[p][s]
    __shared__ __align__(16) unsigned short Mbf[64*72];   // M~ (one head at a time)
    __shared__ __align__(16) unsigned short Cp0[64*16];   // exp(la_h0)*C
    __shared__ __align__(16) unsigned short Cp1[64*16];   // exp(la_h1)*C
    __shared__ float s_hin[256];
    __shared__ float s_dt[64][2], s_nda[64][2], s_la[64][2];
    __shared__ float s_ipw[384], s_ipb2[48], s_cw2[144], s_cb2[48], s_wdt[16];
    __shared__ float s_zw[128], s_ow[128];

    int tid = threadIdx.x;
    int b = blockIdx.x >> 8, c = blockIdx.x & 255;

    {   // hin reconstruction
        int grp = c >> 4;
        float gh  = ghw[(((size_t)b*NGRP + grp) << 8) + tid];
        float cpv = cpw[((size_t)b*NCH + c)*2 + (tid >> 7)];
        float phv = phw[(((size_t)b*NCH + c) << 8) + tid];
        s_hin[tid] = fmaf(cpv, gh, phv);
    }
    for (int i = tid; i < 384; i += 256) s_ipw[i] = ipw[128 + i];
    if (tid < 128) s_zw[tid] = ipw[tid];
    else s_ow[tid-128] = out_w[tid-128];
    if (tid < 48) { s_ipb2[tid] = ipb[16 + tid]; s_cb2[tid] = cb[tid]; }
    else if (tid >= 64 && tid < 208) s_cw2[tid - 64] = cw[tid - 64];
    else if (tid >= 224 && tid < 240) s_wdt[tid - 224] = ipw[512 + (tid - 224)];
    __syncthreads();                                          // B0

    float a0e = __expf(A_log[0]), a1e = __expf(A_log[1]);
    float dtb0 = dt_bias[0], dtb1 = dt_bias[1];
    float bdt0 = ipb[64], bdt1 = ipb[65];
    float D0 = Dv[0], D1 = Dv[1];

    {   // staging: full 48 channels, 4 threads/row x 12 ch
        int r = tid >> 2, sub = tid & 3;
        int l = c*CHN + r;
        size_t gb = ((size_t)b*LL + l)*GG;
        float g0[8], g1[8], g2v[8];
        #pragma unroll
        for (int g = 0; g < 8; ++g) { g1[g] = 0.f; g2v[g] = 0.f; }
        load8(g0, gtw + gb);
        if (l >= 1) load8(g1, gtw + gb - GG);
        if (l >= 2) load8(g2v, gtw + gb - 2*GG);
        #pragma unroll
        for (int k = 0; k < 12; ++k) {
            int ch = sub*12 + k;
            float bia = s_ipb2[ch];
            float tA = bia, tB = bia, tC = bia;
            #pragma unroll
            for (int g = 0; g < 8; ++g) {
                float wv = s_ipw[ch*8+g];
                tA = fmaf(g0[g],  wv, tA);
                tB = fmaf(g1[g],  wv, tB);
                tC = fmaf(g2v[g], wv, tC);
            }
            if (l < 1) tB = 0.f;
            if (l < 2) tC = 0.f;
            float a = s_cb2[ch];
            a = fmaf(tC, s_cw2[ch*3+0], a);
            a = fmaf(tB, s_cw2[ch*3+1], a);
            a = fmaf(tA, s_cw2[ch*3+2], a);
            float v = siluf(a);
            if (ch < 16)      XTbf[ch*72 + r] = f2bf(v);
            else if (ch < 32) Bbf[r*40 + (ch-16)] = f2bf(v);
            else              Cbf[r*40 + (ch-32)] = f2bf(v);
        }
        unsigned int* cz = (unsigned int*)&Cbf[r*40 + 16];
        unsigned int* bz = (unsigned int*)&Bbf[r*40 + 16];
        cz[sub*2+0] = 0u; cz[sub*2+1] = 0u;
        bz[sub*2+0] = 0u; bz[sub*2+1] = 0u;
        if (sub == 0) {
            float d0 = bdt0, d1 = bdt1;
            #pragma unroll
            for (int g = 0; g < 8; ++g) {
                d0 = fmaf(g0[g], s_wdt[g],   d0);
                d1 = fmaf(g0[g], s_wdt[8+g], d1);
            }
            float dt0 = softplusf(d0 + dtb0), dt1 = softplusf(d1 + dtb1);
            s_dt[r][0] = dt0; s_dt[r][1] = dt1;
            s_nda[r][0] = -dt0*a0e; s_nda[r][1] = -dt1*a1e;
        }
    }
    __syncthreads();                                          // B1

    int lane = tid & 63, wv = tid >> 6;
    int ar = lane & 15, kb = lane >> 4;
    int trow = wv*16 + kb*4;

    // G = C.B^T (register results, per wave; causal tiles only)
    f32x4 gT[4];
    {
        bf16x8 aC = *(const bf16x8*)&Cbf[(wv*16 + ar)*40 + kb*8];
        #pragma unroll
        for (int ss = 0; ss < 4; ++ss) {
            f32x4 g = {0.f, 0.f, 0.f, 0.f};
            if (ss <= wv) {
                bf16x8 bB = *(const bf16x8*)&Bbf[(ss*16 + ar)*40 + kb*8];
                g = __builtin_amdgcn_mfma_f32_16x16x32_bf16(aC, bB, g, 0, 0, 0);
            }
            gT[ss] = g;
        }
    }
    if (tid < 64) {   // wave 0: log-cumsum
        int rr = tid;
        float v0 = s_nda[rr][0], v1 = s_nda[rr][1];
        #pragma unroll
        for (int off = 1; off < 64; off <<= 1) {
            float t0 = __shfl_up(v0, off);
            float t1 = __shfl_up(v1, off);
            if (rr >= off) { v0 += t0; v1 += t1; }
        }
        s_la[rr][0] = v0; s_la[rr][1] = v1;
    }
    __syncthreads();                                          // B2

    {   // C' = exp(la)*C, both heads (4 u32 per thread)
        int h = tid >> 7;
        int rr = (tid & 127) >> 1;
        int nh = (tid & 1) * 8;
        float sc = __expf(s_la[rr][h]);
        unsigned short* Cp = h ? Cp1 : Cp0;
        unsigned int* dst = (unsigned int*)&Cp[rr*16 + nh];
        #pragma unroll
        for (int j = 0; j < 4; ++j)
            dst[j] = pack2bf(sc * bf2f(Cbf[rr*40 + nh + j*2]),
                             sc * bf2f(Cbf[rr*40 + nh + j*2 + 1]));
    }
    float lr0 = s_la[wv*16][0], lr1 = s_la[wv*16][1];
    float ef0[4], ef1[4];
    #pragma unroll
    for (int rg = 0; rg < 4; ++rg) {
        ef0[rg] = __expf(s_la[trow+rg][0] - lr0);
        ef1[rg] = __expf(s_la[trow+rg][1] - lr1);
    }
    {   // M~ head0 build (pair-packed dword stores)
        for (int ss = 0; ss < 4; ++ss) {
            int s = ss*16 + ar;
            if (ss > wv) {
                if (!(ar & 1)) {
                    #pragma unroll
                    for (int rg = 0; rg < 4; ++rg)
                        *(unsigned int*)&Mbf[(trow+rg)*72 + ss*16 + ar] = 0u;
                }
                continue;
            }
            float ec0 = __expf(lr0 - s_la[s][0]) * s_dt[s][0];
            #pragma unroll
            for (int rg = 0; rg < 4; ++rg) {
                float m = (s <= trow+rg) ? ef0[rg]*ec0*gT[ss][rg] : 0.f;
                float mp = __shfl_xor(m, 1);
                if (!(ar & 1))
                    *(unsigned int*)&Mbf[(trow+rg)*72 + ss*16 + ar] = pack2bf(m, mp);
            }
        }
    }
    __syncthreads();                                          // B3

    // Y head0 = M~.X + C'h0.hin0
    f32x4 acc0 = {0.f, 0.f, 0.f, 0.f};
    {
        int p = ar;
        #pragma unroll
        for (int kk = 0; kk < 2; ++kk) {
            bf16x8 am = *(const bf16x8*)&Mbf[(wv*16 + ar)*72 + kk*32 + kb*8];
            bf16x8 bx = {0,0,0,0,0,0,0,0};
            if (p < 8) bx = *(const bf16x8*)&XTbf[p*72 + kk*32 + kb*8];
            acc0 = __builtin_amdgcn_mfma_f32_16x16x32_bf16(am, bx, acc0, 0, 0, 0);
        }
        bf16x8 aCp = {0,0,0,0,0,0,0,0};
        if (kb < 2) aCp = *(const bf16x8*)&Cp0[(wv*16 + ar)*16 + kb*8];
        bf16x8 bh = {0,0,0,0,0,0,0,0};
        if (kb < 2) {
            #pragma unroll
            for (int j = 0; j < 8; ++j)
                bh[j] = (short)f2bf(s_hin[0*128 + (ar&7)*16 + kb*8 + j]);
        }
        acc0 = __builtin_amdgcn_mfma_f32_16x16x32_bf16(aCp, bh, acc0, 0, 0, 0);
    }
    __syncthreads();                                          // B4

    {   // M~ head1 build
        for (int ss = 0; ss < 4; ++ss) {
            int s = ss*16 + ar;
            if (ss > wv) {
                if (!(ar & 1)) {
                    #pragma unroll
                    for (int rg = 0; rg < 4; ++rg)
                        *(unsigned int*)&Mbf[(trow+rg)*72 + ss*16 + ar] = 0u;
                }
                continue;
            }
            float ec1 = __expf(lr1 - s_la[s][1]) * s_dt[s][1];
            #pragma unroll
            for (int rg = 0; rg < 4; ++rg) {
                float m = (s <= trow+rg) ? ef1[rg]*ec1*gT[ss][rg] : 0.f;
                float mp = __shfl_xor(m, 1);
                if (!(ar & 1))
                    *(unsigned int*)&Mbf[(trow+rg)*72 + ss*16 + ar] = pack2bf(m, mp);
            }
        }
    }
    __syncthreads();                                          // B5

    // Y head1 + both-head yb store (yb overlays Cbf, dead since B3)
    float* yb = (float*)Cbf;
    {
        int p = ar;
        f32x4 acc1 = {0.f, 0.f, 0.f, 0.f};
        #pragma unroll
        for (int kk = 0; kk < 2; ++kk) {
            bf16x8 am = *(const bf16x8*)&Mbf[(wv*16 + ar)*72 + kk*32 + kb*8];
            bf16x8 bx = {0,0,0,0,0,0,0,0};
            if (p < 8) bx = *(const bf16x8*)&XTbf[(8 + p)*72 + kk*32 + kb*8];
            acc1 = __builtin_amdgcn_mfma_f32_16x16x32_bf16(am, bx, acc1, 0, 0, 0);
        }
        bf16x8 aCp = {0,0,0,0,0,0,0,0};
        if (kb < 2) aCp = *(const bf16x8*)&Cp1[(wv*16 + ar)*16 + kb*8];
        bf16x8 bh = {0,0,0,0,0,0,0,0};
        if (kb < 2) {
            #pragma unroll
            for (int j = 0; j < 8; ++j)
                bh[j] = (short)f2bf(s_hin[1*128 + (ar&7)*16 + kb*8 + j]);
        }
        acc1 = __builtin_amdgcn_mfma_f32_16x16x32_bf16(aCp, bh, acc1, 0, 0, 0);
        if (p < 8) {
            #pragma unroll
            for (int rg = 0; rg < 4; ++rg) {
                int t = trow + rg;
                yb[t*20 + p]     = fmaf(D0, bf2f(XTbf[p*72 + t]),     acc0[rg]);
                yb[t*20 + 8 + p] = fmaf(D1, bf2f(XTbf[(8+p)*72 + t]), acc1[rg]);
            }
        }
    }
    __syncthreads();                                          // B6

    {   // epilogue: quad (r = tid>>2, q = tid&3) -> silu gate, RMSNorm, out proj, residual
        int r = tid >> 2, q = tid & 3;
        float gv[8]; load8(gv, gtw + ((size_t)b*LL + c*CHN + r)*GG);
        float vv[4]; float ssq = 0.f;
        #pragma unroll
        for (int j = 0; j < 4; ++j) {
            int hp = q*4 + j;
            float zz = ipb[hp];
            #pragma unroll
            for (int g = 0; g < 8; ++g) zz = fmaf(gv[g], s_zw[hp*8+g], zz);
            float y = yb[r*20 + hp];
            float w = y * siluf(zz);
            vv[j] = w; ssq = fmaf(w, w, ssq);
        }
        ssq += __shfl_xor(ssq, 1);
        ssq += __shfl_xor(ssq, 2);
        float rn = rsqrtf(ssq*(1.f/16.f) + 1e-5f);
        float o[8];
        #pragma unroll
        for (int g = 0; g < 8; ++g) o[g] = 0.f;
        #pragma unroll
        for (int j = 0; j < 4; ++j) {
            float wj = vv[j] * rn * norm_w[q*4+j];
            #pragma unroll
            for (int g = 0; g < 8; ++g) o[g] = fmaf(wj, s_ow[g*16 + q*4 + j], o[g]);
        }
        #pragma unroll
        for (int g = 0; g < 8; ++g) {
            o[g] += __shfl_xor(o[g], 1);
            o[g] += __shfl_xor(o[g], 2);
        }
        if (q == 0) {
            #pragma unroll
            for (int g = 0; g < 8; ++g) o[g] += out_b[g] + gv[g];
            float* gp = g2w + ((size_t)b*LL + c*CHN + r)*GG;
            ((float4*)gp)[0] = make_float4(o[0],o[1],o[2],o[3]);
            ((float4*)gp)[1] = make_float4(o[4],o[5],o[6],o[7]);
        }
    }
}

// K5b: out = x + detok(g2) + detok_b.  1024 blocks x 64 threads.
__global__ __launch_bounds__(64) void k5b_detok(
    const float* __restrict__ x, const float* __restrict__ g2w,
    const float* __restrict__ dkw, const float* __restrict__ dkb,
    float* __restrict__ outp)
{
    __shared__ float s_dw[CF*GG];
    __shared__ float s_db[CF];
    int tid = threadIdx.x;
    int b  = blockIdx.x >> 6;
    int ck = blockIdx.x & 63;
    int l0 = (ck << 8) + (tid << 2);
    for (int i = tid; i < CF*GG; i += 64) s_dw[i] = dkw[i];
    s_db[tid] = dkb[tid];
    __syncthreads();
    float g2v[4][8];
    const float* gp = g2w + ((size_t)b*LL + l0)*GG;
    #pragma unroll
    for (int r = 0; r < 4; ++r) load8(g2v[r], gp + r*GG);
    const float* xb = x + (size_t)b*CF*LL + l0;
    float* ob = outp + (size_t)b*CF*LL + l0;
    #pragma unroll 4
    for (int c = 0; c < CF; ++c) {
        float4 xv = *(const float4*)(xb + (size_t)c*LL);
        float bias = s_db[c];
        float oa[4] = {xv.x+bias, xv.y+bias, xv.z+bias, xv.w+bias};
        #pragma unroll
        for (int g = 0; g < GG; ++g) {
            float w = s_dw[c*GG+g];
            #pragma unroll
            for (int r = 0; r < 4; ++r) oa[r] = fmaf(g2v[r][g], w, oa[r]);
        }
        *(float4*)(ob + (size_t)c*LL) = make_float4(oa[0],oa[1],oa[2],oa[3]);
    }
}

extern "C" void kernel_launch(void* const* d_in, const int* in_sizes, int n_in,
                              void* d_out, int out_size, void* d_ws, size_t ws_size,
                              hipStream_t stream) {
    const float* x       = (const float*)d_in[0];
    const float* tok_w   = (const float*)d_in[1];
    const float* tok_b   = (const float*)d_in[2];
    const float* detok_w = (const float*)d_in[3];
    const float* detok_b = (const float*)d_in[4];
    const float* ipw     = (const float*)d_in[5];
    const float* ipb     = (const float*)d_in[6];
    const float* cw      = (const float*)d_in[7];
    const float* cb      = (const float*)d_in[8];
    const float* A_log   = (const float*)d_in[9];
    const float* Dv      = (const float*)d_in[10];
    const float* dt_bias = (const float*)d_in[11];
    const float* norm_w  = (const float*)d_in[12];
    const float* out_w   = (const float*)d_in[13];
    const float* out_b   = (const float*)d_in[14];
    float* ws = (float*)d_ws;
    float* outp = (float*)d_out;

    if (ws_size < WS_FLOATS * sizeof(float)) return;

    k1a_tok<<<NB*64, 64, 0, stream>>>(x, tok_w, tok_b, ws+OFF_GT);
    k2a_state<<<NB*NCH, 256, 0, stream>>>(ws+OFF_GT, ipw, ipb, cw, cb,
        A_log, dt_bias, ws+OFF_U2, ws+OFF_AC);
    k4c1<<<NB*NGRP, 256, 0, stream>>>(ws+OFF_U2, ws+OFF_AC,
        ws+OFF_PH, ws+OFF_CP, ws+OFF_UG, ws+OFF_AG);
    k4c2<<<NB, 256, 0, stream>>>(ws+OFF_UG, ws+OFF_AG, ws+OFF_GH);
    k2b_fused<<<NB*NCH, 256, 0, stream>>>(ws+OFF_GT, ipw, ipb, cw, cb,
        A_log, dt_bias, Dv, norm_w, out_w, out_b,
        ws+OFF_PH, ws+OFF_CP, ws+OFF_GH, ws+OFF_G2);
    k5b_detok<<<NB*64, 64, 0, stream>>>(x, ws+OFF_G2, detok_w, detok_b, outp);
}